// Round 3
// baseline (19322.441 us; speedup 1.0000x reference)
//
#include <hip/hip_runtime.h>
#include <hip/hip_cooperative_groups.h>

namespace cg = cooperative_groups;

#define BS 256
#define IN_LEN 512
#define T_OUT 64
#define H 1024
#define G4 4096

typedef __attribute__((ext_vector_type(8))) short bf16x8;
typedef __attribute__((ext_vector_type(4))) float f32x4;

__device__ __forceinline__ unsigned short f2bf(float x) {
    union { float f; unsigned u; } v; v.f = x;
    unsigned r = v.u + 0x7fffu + ((v.u >> 16) & 1u);   // RTNE
    return (unsigned short)(r >> 16);
}
__device__ __forceinline__ float bf2f(unsigned short b) {
    union { unsigned u; float f; } v; v.u = ((unsigned)b) << 16;
    return v.f;
}
__device__ __forceinline__ float sigf(float x) { return 1.f / (1.f + __expf(-x)); }
__device__ __forceinline__ float tanhfast(float x) { return 1.f - 2.f / (__expf(2.f * x) + 1.f); }

__device__ __forceinline__ void gl_lds16(const void* g, void* l) {
    __builtin_amdgcn_global_load_lds((const __attribute__((address_space(1))) void*)g,
                                     (__attribute__((address_space(3))) void*)l, 16, 0, 0);
}

// ---- pack Wc = w_ih + w_hh into bf16 hi/lo, rows permuted p = hh*4+gate; also split w_out
__global__ __launch_bounds__(256) void k_prep(const float4* __restrict__ w_ih4,
                                              const float4* __restrict__ w_hh4,
                                              const float4* __restrict__ w_out4,
                                              ushort4* __restrict__ Wch, ushort4* __restrict__ Wcl,
                                              ushort4* __restrict__ woh, ushort4* __restrict__ wol) {
    int row = blockIdx.x;        // source row 0..4095 (gate-major)
    int c4 = threadIdx.x;        // 0..255 float4 cols
    float4 a = w_ih4[row * 256 + c4];
    float4 b = w_hh4[row * 256 + c4];
    int p = ((row & 1023) << 2) | (row >> 10);   // packed row hh*4+gate
    float sx = a.x + b.x, sy = a.y + b.y, sz = a.z + b.z, sw = a.w + b.w;
    ushort4 hi, lo;
    hi.x = f2bf(sx); lo.x = f2bf(sx - bf2f(hi.x));
    hi.y = f2bf(sy); lo.y = f2bf(sy - bf2f(hi.y));
    hi.z = f2bf(sz); lo.z = f2bf(sz - bf2f(hi.z));
    hi.w = f2bf(sw); lo.w = f2bf(sw - bf2f(hi.w));
    Wch[p * 256 + c4] = hi;
    Wcl[p * 256 + c4] = lo;
    if (row < 64) {
        float4 w = w_out4[row * 256 + c4];
        ushort4 h2, l2;
        h2.x = f2bf(w.x); l2.x = f2bf(w.x - bf2f(h2.x));
        h2.y = f2bf(w.y); l2.y = f2bf(w.y - bf2f(h2.y));
        h2.z = f2bf(w.z); l2.z = f2bf(w.z - bf2f(h2.z));
        h2.w = f2bf(w.w); l2.w = f2bf(w.w - bf2f(h2.w));
        woh[row * 256 + c4] = h2;
        wol[row * 256 + c4] = l2;
    }
}

// ---- g0p[p] = dot(start_token, w_ih[row]) + b_ih + b_hh (packed); bcp[p] = b_ih+b_hh
__global__ __launch_bounds__(256) void k_g0(const float4* __restrict__ st4,
                                            const float4* __restrict__ w_ih4,
                                            const float* __restrict__ b_ih,
                                            const float* __restrict__ b_hh,
                                            float* __restrict__ g0p, float* __restrict__ bcp) {
    int j = (blockIdx.x * 256 + threadIdx.x) >> 6;   // source row 0..4095
    int lane = threadIdx.x & 63;
    float s = 0.f;
#pragma unroll
    for (int q = 0; q < 4; ++q) {
        int idx = q * 64 + lane;
        float4 w4 = w_ih4[(size_t)j * 256 + idx];
        float4 s4 = st4[idx];
        s += w4.x * s4.x + w4.y * s4.y + w4.z * s4.z + w4.w * s4.w;
    }
#pragma unroll
    for (int off = 32; off > 0; off >>= 1) s += __shfl_down(s, off, 64);
    if (lane == 0) {
        int p = ((j & 1023) << 2) | (j >> 10);
        float bb = b_ih[j] + b_hh[j];
        bcp[p] = bb;
        g0p[p] = s + bb;
    }
}

// ---- h0 = einsum("bih,i->bh") + b_in, split to bf16 hi/lo; c = 0
__global__ __launch_bounds__(256) void k_h0(const float4* __restrict__ qf4,
                                            const float* __restrict__ w_in,
                                            const float* __restrict__ b_in,
                                            ushort4* __restrict__ h_hi, ushort4* __restrict__ h_lo,
                                            float4* __restrict__ c4) {
    int idx = blockIdx.x * 256 + threadIdx.x;
    int b = idx >> 8;
    int hq = idx & 255;
    const float4* p = qf4 + (size_t)b * IN_LEN * 256 + hq;
    float4 s = make_float4(0.f, 0.f, 0.f, 0.f);
#pragma unroll 4
    for (int i = 0; i < IN_LEN; ++i) {
        float w = w_in[i];
        float4 q = p[(size_t)i * 256];
        s.x += q.x * w; s.y += q.y * w; s.z += q.z * w; s.w += q.w * w;
    }
    float bi = b_in[0];
    s.x += bi; s.y += bi; s.z += bi; s.w += bi;
    ushort4 hi, lo;
    hi.x = f2bf(s.x); lo.x = f2bf(s.x - bf2f(hi.x));
    hi.y = f2bf(s.y); lo.y = f2bf(s.y - bf2f(hi.y));
    hi.z = f2bf(s.z); lo.z = f2bf(s.z - bf2f(hi.z));
    hi.w = f2bf(s.w); lo.w = f2bf(s.w - bf2f(hi.w));
    h_hi[idx] = hi;
    h_lo[idx] = lo;
    c4[idx] = make_float4(0.f, 0.f, 0.f, 0.f);
}

// ---- step 0 only: gates = h0 @ w_hh^T (fp32 src, split on the fly) + g0, then cell
__global__ __launch_bounds__(256) void k_step(const float* __restrict__ Bf,   // w_hh fp32
                                              const float* __restrict__ bias, // g0 packed [4096]
                                              const ushort* __restrict__ Ah,
                                              const ushort* __restrict__ Al,
                                              float* __restrict__ c,
                                              ushort* __restrict__ Oh, ushort* __restrict__ Ol,
                                              float* __restrict__ out_h, int t) {
    __shared__ __align__(16) ushort sAh[64 * 32], sAl[64 * 32], sBh[64 * 32], sBl[64 * 32];
    __shared__ __align__(16) float sC[64 * 68];

    const int tid = threadIdx.x;
    const int n0 = blockIdx.x * 64;
    const int m0 = blockIdx.y * 64;
    const int w = tid >> 6, l = tid & 63;
    const int wm = w & 1, wn = w >> 1;
    const int lm = l & 15, kg = l >> 4;

    const int srow = tid >> 2;
    const int scol = (tid & 3) * 8;
    const int ldsOff = (tid >> 6) * 512;

    const ushort* gAh = Ah + (m0 + srow) * H + scol;
    const ushort* gAl = Al + (m0 + srow) * H + scol;
    const int prow = n0 + srow;
    const float* gBf = Bf + ((size_t)(prow & 3) * H + (prow >> 2)) * H + scol;

    f32x4 acc[2][2];
#pragma unroll
    for (int mi = 0; mi < 2; ++mi)
#pragma unroll
        for (int ni = 0; ni < 2; ++ni) acc[mi][ni] = (f32x4)(0.f);

#pragma unroll 1
    for (int ch = 0; ch < H / 32; ++ch) {
        const int k0 = ch * 32;
        __syncthreads();
        float4 f0 = *(const float4*)(gBf + k0);
        float4 f1 = *(const float4*)(gBf + k0 + 4);
        ushort4 h0_, h1_, l0_, l1_;
        h0_.x = f2bf(f0.x); l0_.x = f2bf(f0.x - bf2f(h0_.x));
        h0_.y = f2bf(f0.y); l0_.y = f2bf(f0.y - bf2f(h0_.y));
        h0_.z = f2bf(f0.z); l0_.z = f2bf(f0.z - bf2f(h0_.z));
        h0_.w = f2bf(f0.w); l0_.w = f2bf(f0.w - bf2f(h0_.w));
        h1_.x = f2bf(f1.x); l1_.x = f2bf(f1.x - bf2f(h1_.x));
        h1_.y = f2bf(f1.y); l1_.y = f2bf(f1.y - bf2f(h1_.y));
        h1_.z = f2bf(f1.z); l1_.z = f2bf(f1.z - bf2f(h1_.z));
        h1_.w = f2bf(f1.w); l1_.w = f2bf(f1.w - bf2f(h1_.w));
        int si = srow * 32 + (tid & 3) * 8;
        *(ushort4*)&sBh[si] = h0_; *(ushort4*)&sBh[si + 4] = h1_;
        *(ushort4*)&sBl[si] = l0_; *(ushort4*)&sBl[si + 4] = l1_;
        gl_lds16(gAh + k0, &sAh[ldsOff]);
        gl_lds16(gAl + k0, &sAl[ldsOff]);
        __syncthreads();

        bf16x8 ah[2], al[2], bh[2], bl[2];
#pragma unroll
        for (int mi = 0; mi < 2; ++mi) {
            int base = (wm * 32 + mi * 16 + lm) * 32 + kg * 8;
            ah[mi] = *(const bf16x8*)&sAh[base];
            al[mi] = *(const bf16x8*)&sAl[base];
        }
#pragma unroll
        for (int ni = 0; ni < 2; ++ni) {
            int base = (wn * 32 + ni * 16 + lm) * 32 + kg * 8;
            bh[ni] = *(const bf16x8*)&sBh[base];
            bl[ni] = *(const bf16x8*)&sBl[base];
        }
#pragma unroll
        for (int mi = 0; mi < 2; ++mi)
#pragma unroll
            for (int ni = 0; ni < 2; ++ni) {
                acc[mi][ni] = __builtin_amdgcn_mfma_f32_16x16x32_bf16(ah[mi], bh[ni], acc[mi][ni], 0, 0, 0);
                acc[mi][ni] = __builtin_amdgcn_mfma_f32_16x16x32_bf16(ah[mi], bl[ni], acc[mi][ni], 0, 0, 0);
                acc[mi][ni] = __builtin_amdgcn_mfma_f32_16x16x32_bf16(al[mi], bh[ni], acc[mi][ni], 0, 0, 0);
            }
    }

#pragma unroll
    for (int mi = 0; mi < 2; ++mi)
#pragma unroll
        for (int ni = 0; ni < 2; ++ni) {
            int r0 = wm * 32 + mi * 16 + kg * 4;
            int c0_ = wn * 32 + ni * 16 + lm;
#pragma unroll
            for (int r = 0; r < 4; ++r) sC[(r0 + r) * 68 + c0_] = acc[mi][ni][r];
        }
    __syncthreads();

#pragma unroll
    for (int q = 0; q < 4; ++q) {
        int cid = tid + q * 256;
        int bl_ = cid >> 4, hl = cid & 15;
        float4 gv = *(const float4*)&sC[bl_ * 68 + hl * 4];
        float4 bv = *(const float4*)&bias[n0 + hl * 4];
        int b = m0 + bl_;
        int hh = (n0 >> 2) + hl;
        float cold = c[b * H + hh];
        float ig = gv.x + bv.x, fg = gv.y + bv.y, gg = gv.z + bv.z, og = gv.w + bv.w;
        float cn = sigf(fg) * cold + sigf(ig) * tanhfast(gg);
        float hn = sigf(og) * tanhfast(cn);
        c[b * H + hh] = cn;
        unsigned short hb = f2bf(hn);
        Oh[b * H + hh] = hb;
        Ol[b * H + hh] = f2bf(hn - bf2f(hb));
        out_h[(b * T_OUT + t) * H + hh] = hn;
    }
}

// ---- persistent cooperative kernel: steps t=1..63
// 256 blocks x 256 threads. Block b: n = b&63 (packed-col tile), m = b>>6 (batch tile)
// => each XCD's 32 blocks cover 8 n-tiles x 4 m-tiles (W slice + A tile L2-resident).
// c-state in registers; A double-buffered in LDS (pad 40 => 2-way banks, free);
// B fragments direct from L2-resident global into registers (prefetch depth 1).
__global__ __launch_bounds__(256) void k_rnn(const ushort* __restrict__ Wch,
                                             const ushort* __restrict__ Wcl,
                                             const float* __restrict__ bcp,
                                             ushort* __restrict__ hA_h, ushort* __restrict__ hA_l,
                                             ushort* __restrict__ hB_h, ushort* __restrict__ hB_l,
                                             const float* __restrict__ cb_in,
                                             float* __restrict__ out_h) {
    cg::grid_group grid = cg::this_grid();
    __shared__ __align__(16) ushort sA[2][2][64 * 40];   // [buf][hi/lo][row*40+k]
    __shared__ __align__(16) float sC[64 * 68];
    __shared__ __align__(16) float sBias[64];

    const int tid = threadIdx.x;
    const int blk = blockIdx.x;
    const int n = blk & 63, m = blk >> 6;
    const int n0 = n * 64;           // packed col base
    const int m0 = m * 64;           // batch base
    const int w = tid >> 6, l = tid & 63;
    const int wm = w & 1, wn = w >> 1;
    const int lm = l & 15, kg = l >> 4;
    const int srow = tid >> 2;       // A staging row 0..63
    const int skoff = (tid & 3) * 8; // A staging k-offset (ushorts)

    if (tid < 16) ((float4*)sBias)[tid] = ((const float4*)(bcp + n0))[tid];

    // c-state + output indices (fixed for all steps)
    float c_reg[4];
    int bidx[4], hidx[4];
#pragma unroll
    for (int q = 0; q < 4; ++q) {
        int cid = tid + q * 256;
        int bl_ = cid >> 4, hl = cid & 15;
        bidx[q] = m0 + bl_;
        hidx[q] = n * 16 + hl;
        c_reg[q] = cb_in[bidx[q] * H + hidx[q]];
    }

    // B fragment global pointers (k advances by ch*32 ushorts)
    const ushort* pBh[2];
    const ushort* pBl[2];
#pragma unroll
    for (int ni = 0; ni < 2; ++ni) {
        int row = n0 + wn * 32 + ni * 16 + lm;
        pBh[ni] = Wch + (size_t)row * H + kg * 8;
        pBl[ni] = Wcl + (size_t)row * H + kg * 8;
    }

#pragma unroll 1
    for (int t = 1; t < T_OUT; ++t) {
        const ushort* Ah = (t & 1) ? hB_h : hA_h;
        const ushort* Al = (t & 1) ? hB_l : hA_l;
        ushort* Oh = (t & 1) ? hA_h : hB_h;
        ushort* Ol = (t & 1) ? hA_l : hB_l;

        const ushort* gAh = Ah + (m0 + srow) * H + skoff;
        const ushort* gAl = Al + (m0 + srow) * H + skoff;
        const int sAidx = srow * 40 + skoff;

        f32x4 acc[2][2];
#pragma unroll
        for (int mi = 0; mi < 2; ++mi)
#pragma unroll
            for (int ni = 0; ni < 2; ++ni) acc[mi][ni] = (f32x4)(0.f);

        // preamble: stage chunk 0, prefetch chunk 1 (A regs) and chunk 0 (B regs)
        uint4 rah = *(const uint4*)gAh;
        uint4 ral = *(const uint4*)gAl;
        *(uint4*)&sA[0][0][sAidx] = rah;
        *(uint4*)&sA[0][1][sAidx] = ral;
        rah = *(const uint4*)(gAh + 32);
        ral = *(const uint4*)(gAl + 32);
        bf16x8 bh[2][2], bl[2][2];   // [set][ni]
#pragma unroll
        for (int ni = 0; ni < 2; ++ni) {
            bh[0][ni] = *(const bf16x8*)(pBh[ni]);
            bl[0][ni] = *(const bf16x8*)(pBl[ni]);
        }
        __syncthreads();

#pragma unroll 1
        for (int ch = 0; ch < 32; ++ch) {
            const int cs = ch & 1, ns = cs ^ 1;
            if (ch + 1 < 32) {
                *(uint4*)&sA[ns][0][sAidx] = rah;        // stage chunk ch+1
                *(uint4*)&sA[ns][1][sAidx] = ral;
#pragma unroll
                for (int ni = 0; ni < 2; ++ni) {          // prefetch B chunk ch+1
                    bh[ns][ni] = *(const bf16x8*)(pBh[ni] + (ch + 1) * 32);
                    bl[ns][ni] = *(const bf16x8*)(pBl[ni] + (ch + 1) * 32);
                }
            }
            if (ch + 2 < 32) {                            // prefetch A chunk ch+2
                rah = *(const uint4*)(gAh + (ch + 2) * 32);
                ral = *(const uint4*)(gAl + (ch + 2) * 32);
            }
            bf16x8 ah[2], al[2];
#pragma unroll
            for (int mi = 0; mi < 2; ++mi) {
                int base = (wm * 32 + mi * 16 + lm) * 40 + kg * 8;
                ah[mi] = *(const bf16x8*)&sA[cs][0][base];
                al[mi] = *(const bf16x8*)&sA[cs][1][base];
            }
#pragma unroll
            for (int mi = 0; mi < 2; ++mi)
#pragma unroll
                for (int ni = 0; ni < 2; ++ni) {
                    acc[mi][ni] = __builtin_amdgcn_mfma_f32_16x16x32_bf16(ah[mi], bh[cs][ni], acc[mi][ni], 0, 0, 0);
                    acc[mi][ni] = __builtin_amdgcn_mfma_f32_16x16x32_bf16(ah[mi], bl[cs][ni], acc[mi][ni], 0, 0, 0);
                    acc[mi][ni] = __builtin_amdgcn_mfma_f32_16x16x32_bf16(al[mi], bh[cs][ni], acc[mi][ni], 0, 0, 0);
                }
            __syncthreads();
        }

        // epilogue: C tile -> LDS -> per-thread (i,f,g,o) gather -> cell -> stores
#pragma unroll
        for (int mi = 0; mi < 2; ++mi)
#pragma unroll
            for (int ni = 0; ni < 2; ++ni) {
                int r0 = wm * 32 + mi * 16 + kg * 4;
                int c0_ = wn * 32 + ni * 16 + lm;
#pragma unroll
                for (int r = 0; r < 4; ++r) sC[(r0 + r) * 68 + c0_] = acc[mi][ni][r];
            }
        __syncthreads();

#pragma unroll
        for (int q = 0; q < 4; ++q) {
            int cid = tid + q * 256;
            int bl_ = cid >> 4, hl = cid & 15;
            float4 gv = *(const float4*)&sC[bl_ * 68 + hl * 4];
            float4 bv = *(const float4*)&sBias[hl * 4];
            float ig = gv.x + bv.x, fg = gv.y + bv.y, gg = gv.z + bv.z, og = gv.w + bv.w;
            float cn = sigf(fg) * c_reg[q] + sigf(ig) * tanhfast(gg);
            float hn = sigf(og) * tanhfast(cn);
            c_reg[q] = cn;
            int b = bidx[q], hh = hidx[q];
            unsigned short hb = f2bf(hn);
            Oh[b * H + hh] = hb;
            Ol[b * H + hh] = f2bf(hn - bf2f(hb));
            out_h[(b * T_OUT + t) * H + hh] = hn;
        }

        grid.sync();
    }
}

// ---- probs = hs @ w_out^T + b_out  (split-bf16 MFMA)
__global__ __launch_bounds__(256) void k_probs(const float* __restrict__ hs,
                                               const ushort* __restrict__ Bh,
                                               const ushort* __restrict__ Bl,
                                               const float* __restrict__ b_out,
                                               float* __restrict__ probs) {
    __shared__ __align__(16) ushort sAh[64 * 32], sAl[64 * 32], sBh[64 * 32], sBl[64 * 32];
    const int tid = threadIdx.x;
    const int r0 = blockIdx.x * 64;
    const int w = tid >> 6, l = tid & 63;
    const int wm = w & 1, wn = w >> 1;
    const int lm = l & 15, kg = l >> 4;
    const int srow = tid >> 2;
    const int scol = (tid & 3) * 8;
    const int ldsOff = (tid >> 6) * 512;

    const float* gA = hs + (size_t)(r0 + srow) * H + scol;
    const ushort* gBh = Bh + srow * H + scol;
    const ushort* gBl = Bl + srow * H + scol;

    f32x4 acc[2][2];
#pragma unroll
    for (int mi = 0; mi < 2; ++mi)
#pragma unroll
        for (int ni = 0; ni < 2; ++ni) acc[mi][ni] = (f32x4)(0.f);

#pragma unroll 1
    for (int ch = 0; ch < H / 32; ++ch) {
        const int k0 = ch * 32;
        __syncthreads();
        gl_lds16(gBh + k0, &sBh[ldsOff]);
        gl_lds16(gBl + k0, &sBl[ldsOff]);
        float4 f0 = *(const float4*)(gA + k0);
        float4 f1 = *(const float4*)(gA + k0 + 4);
        ushort4 h0_, h1_, l0_, l1_;
        h0_.x = f2bf(f0.x); l0_.x = f2bf(f0.x - bf2f(h0_.x));
        h0_.y = f2bf(f0.y); l0_.y = f2bf(f0.y - bf2f(h0_.y));
        h0_.z = f2bf(f0.z); l0_.z = f2bf(f0.z - bf2f(h0_.z));
        h0_.w = f2bf(f0.w); l0_.w = f2bf(f0.w - bf2f(h0_.w));
        h1_.x = f2bf(f1.x); l1_.x = f2bf(f1.x - bf2f(h1_.x));
        h1_.y = f2bf(f1.y); l1_.y = f2bf(f1.y - bf2f(h1_.y));
        h1_.z = f2bf(f1.z); l1_.z = f2bf(f1.z - bf2f(h1_.z));
        h1_.w = f2bf(f1.w); l1_.w = f2bf(f1.w - bf2f(h1_.w));
        int si = srow * 32 + (tid & 3) * 8;
        *(ushort4*)&sAh[si] = h0_; *(ushort4*)&sAh[si + 4] = h1_;
        *(ushort4*)&sAl[si] = l0_; *(ushort4*)&sAl[si + 4] = l1_;
        __syncthreads();

        bf16x8 ah[2], al[2], bh[2], bl[2];
#pragma unroll
        for (int mi = 0; mi < 2; ++mi) {
            int base = (wm * 32 + mi * 16 + lm) * 32 + kg * 8;
            ah[mi] = *(const bf16x8*)&sAh[base];
            al[mi] = *(const bf16x8*)&sAl[base];
        }
#pragma unroll
        for (int ni = 0; ni < 2; ++ni) {
            int base = (wn * 32 + ni * 16 + lm) * 32 + kg * 8;
            bh[ni] = *(const bf16x8*)&sBh[base];
            bl[ni] = *(const bf16x8*)&sBl[base];
        }
#pragma unroll
        for (int mi = 0; mi < 2; ++mi)
#pragma unroll
            for (int ni = 0; ni < 2; ++ni) {
                acc[mi][ni] = __builtin_amdgcn_mfma_f32_16x16x32_bf16(ah[mi], bh[ni], acc[mi][ni], 0, 0, 0);
                acc[mi][ni] = __builtin_amdgcn_mfma_f32_16x16x32_bf16(ah[mi], bl[ni], acc[mi][ni], 0, 0, 0);
                acc[mi][ni] = __builtin_amdgcn_mfma_f32_16x16x32_bf16(al[mi], bh[ni], acc[mi][ni], 0, 0, 0);
            }
    }

#pragma unroll
    for (int mi = 0; mi < 2; ++mi)
#pragma unroll
        for (int ni = 0; ni < 2; ++ni) {
            int col = wn * 32 + ni * 16 + lm;
            float bo = b_out[col];
            int rowb = r0 + wm * 32 + mi * 16 + kg * 4;
#pragma unroll
            for (int r = 0; r < 4; ++r)
                probs[(size_t)(rowb + r) * 64 + col] = acc[mi][ni][r] + bo;
        }
}

extern "C" void kernel_launch(void* const* d_in, const int* in_sizes, int n_in,
                              void* d_out, int out_size, void* d_ws, size_t ws_size,
                              hipStream_t stream) {
    const float* qf    = (const float*)d_in[1];
    const float* st    = (const float*)d_in[4];
    const float* w_in  = (const float*)d_in[5];
    const float* b_in  = (const float*)d_in[6];
    const float* w_ih  = (const float*)d_in[7];
    const float* w_hh  = (const float*)d_in[8];
    const float* b_ih  = (const float*)d_in[9];
    const float* b_hh  = (const float*)d_in[10];
    const float* w_out = (const float*)d_in[11];
    const float* b_out = (const float*)d_in[12];

    float* probs = (float*)d_out;                        // [256][64][64]
    float* out_h = probs + (size_t)BS * T_OUT * 64;      // [256][64][1024]

    char* ws = (char*)d_ws;
    ushort* Wch = (ushort*)ws; ws += (size_t)G4 * H * 2;
    ushort* Wcl = (ushort*)ws; ws += (size_t)G4 * H * 2;
    ushort* woh = (ushort*)ws; ws += (size_t)64 * H * 2;
    ushort* wol = (ushort*)ws; ws += (size_t)64 * H * 2;
    float*  bcp = (float*)ws;  ws += G4 * 4;
    float*  g0p = (float*)ws;  ws += G4 * 4;
    ushort* hAh = (ushort*)ws; ws += (size_t)BS * H * 2;
    ushort* hAl = (ushort*)ws; ws += (size_t)BS * H * 2;
    ushort* hBh = (ushort*)ws; ws += (size_t)BS * H * 2;
    ushort* hBl = (ushort*)ws; ws += (size_t)BS * H * 2;
    float*  cb  = (float*)ws;  ws += (size_t)BS * H * 4;

    k_prep<<<G4, 256, 0, stream>>>((const float4*)w_ih, (const float4*)w_hh, (const float4*)w_out,
                                   (ushort4*)Wch, (ushort4*)Wcl, (ushort4*)woh, (ushort4*)wol);
    k_g0<<<G4 / 4, 256, 0, stream>>>((const float4*)st, (const float4*)w_ih, b_ih, b_hh, g0p, bcp);
    k_h0<<<BS * H / 4 / 256, 256, 0, stream>>>((const float4*)qf, w_in, b_in,
                                               (ushort4*)hAh, (ushort4*)hAl, (float4*)cb);

    // step 0: h0 (in hA) -> writes hB, c
    k_step<<<dim3(64, 4), 256, 0, stream>>>(w_hh, g0p, hAh, hAl, cb, hBh, hBl, out_h, 0);

    // steps 1..63: persistent cooperative kernel
    void* args[] = {(void*)&Wch, (void*)&Wcl, (void*)&bcp,
                    (void*)&hAh, (void*)&hAl, (void*)&hBh, (void*)&hBl,
                    (void*)&cb, (void*)&out_h};
    hipLaunchCooperativeKernel((const void*)k_rnn, dim3(256), dim3(256), args, 0, stream);

    k_probs<<<BS * T_OUT / 64, 256, 0, stream>>>(out_h, woh, wol, b_out, probs);
}